// Round 13
// baseline (853.835 us; speedup 1.0000x reference)
//
#include <hip/hip_runtime.h>

typedef unsigned short u16;
typedef __attribute__((ext_vector_type(4))) unsigned short u16x4;
typedef __attribute__((ext_vector_type(8))) short short8;
typedef __attribute__((ext_vector_type(4))) float f32x4;

#define DEV static __device__ __forceinline__

constexpr int NB   = 16;
constexpr int S    = 512;
constexpr int DM   = 4096;
constexpr int NH   = 32;
constexpr int NKV  = 8;
constexpr int HD   = 128;
constexpr int TOK  = NB * S;          // 8192
constexpr int NQKV = 6144;            // 4096 q + 1024 k + 1024 v
constexpr float ATT_SCALE = 0.08838834764831845f;  // 1/sqrt(128)

DEV u16 f2b(float f) {
  union { float f; unsigned u; } v; v.f = f;
  unsigned r = v.u + 0x7fffu + ((v.u >> 16) & 1u);
  return (u16)(r >> 16);
}
DEV float b2f(u16 u) {
  union { unsigned u; float f; } v; v.u = ((unsigned)u) << 16;
  return v.f;
}
DEV unsigned cvt_pk_bf16(float lo, float hi) {
  unsigned r;
  asm("v_cvt_pk_bf16_f32 %0, %1, %2" : "=v"(r) : "v"(lo), "v"(hi));
  return r;
}
DEV void async16(const void* g, void* l) {
  __builtin_amdgcn_global_load_lds(
      (const __attribute__((address_space(1))) unsigned int*)g,
      (__attribute__((address_space(3))) unsigned int*)l, 16, 0, 0);
}

// =======================================================================================
// Fused pre-GEMM prep (1 launch): cvt X | rope_tab | tr_w Wq | tr_w Wk | tr_w Wv.
// =======================================================================================
__global__ __launch_bounds__(256) void k_prep(const float* __restrict__ hs,
                                              const float* __restrict__ Wq,
                                              const float* __restrict__ Wk,
                                              const float* __restrict__ Wv,
                                              const int* __restrict__ pos,
                                              u16* __restrict__ X,
                                              u16* __restrict__ WT,
                                              float2* __restrict__ tab) {
  __shared__ float tile[32][33];
  int blk = blockIdx.x;
  const int tid = threadIdx.x;
  if (blk < 32768) {                       // ---- cvt X: f32 -> bf16, float4/lane
    int i = (blk * 256 + tid) * 4;
    const float4 v = *reinterpret_cast<const float4*>(hs + i);
    u16x4 o;
    o[0] = f2b(v.x); o[1] = f2b(v.y); o[2] = f2b(v.z); o[3] = f2b(v.w);
    *reinterpret_cast<u16x4*>(X + i) = o;
    return;
  }
  blk -= 32768;
  if (blk < 2048) {                        // ---- RoPE cos/sin table (4 tokens/block)
    int t = blk * 4 + (tid >> 6);
    int j = tid & 63;
    float p = (float)pos[t];
    float inv = expf(-(float)j * 0.21586735246819178f);
    float sv, cv;
    sincosf(p * inv, &sv, &cv);
    tab[t * 64 + j] = make_float2(cv, sv);
    return;
  }
  blk -= 2048;
  const float* src; u16* dst; int ncols, bx, by;
  if (blk < 16384) {                       // ---- tr Wq
    src = Wq; dst = WT; ncols = 4096; bx = blk & 127; by = blk >> 7;
  } else if (blk < 20480) {                // ---- tr Wk
    blk -= 16384;
    src = Wk; dst = WT + (size_t)4096 * 4096; ncols = 1024; bx = blk & 31; by = blk >> 5;
  } else {                                 // ---- tr Wv
    blk -= 20480;
    src = Wv; dst = WT + (size_t)5120 * 4096; ncols = 1024; bx = blk & 31; by = blk >> 5;
  }
  const int tx = tid & 31, ty = tid >> 5;
  const int n0 = bx * 32, k0 = by * 32;
#pragma unroll
  for (int i = 0; i < 32; i += 8)
    tile[ty + i][tx] = src[(size_t)(k0 + ty + i) * ncols + n0 + tx];
  __syncthreads();
#pragma unroll
  for (int i = 0; i < 32; i += 8)
    dst[(size_t)(n0 + ty + i) * 4096 + k0 + tx] = f2b(tile[tx][ty + i]);
}

// =======================================================================================
// Fused post-GEMM1 prep (1 launch): norm_rope | tr_v | tr_w Wo.
// =======================================================================================
__global__ __launch_bounds__(256) void k_post(u16* __restrict__ qkv,
                                              const float2* __restrict__ tab,
                                              const float* __restrict__ qw,
                                              const float* __restrict__ kw,
                                              u16* __restrict__ vt,
                                              const float* __restrict__ Wo,
                                              u16* __restrict__ wot) {
  __shared__ float ftile[32][33];
  __shared__ u16 utile[32][33];
  int blk = blockIdx.x;
  const int tid = threadIdx.x;
  if (blk < 10240) {                       // ---- fused RMSNorm + RoPE (vectorized)
    int wid  = blk * 4 + (tid >> 6);
    int lane = tid & 63;
    int gr = wid * 8 + (lane >> 3);
    int t  = gr / 40;
    int hh = gr - t * 40;
    bool isq = hh < 32;
    u16* base = qkv + (size_t)t * NQKV + (isq ? hh * 128 : 4096 + (hh - 32) * 128);
    int d0 = (lane & 7) * 8;
    short8 v1 = *reinterpret_cast<const short8*>(base + d0);
    short8 v2 = *reinterpret_cast<const short8*>(base + d0 + 64);
    float x1[8], x2[8];
    float ss = 0.f;
#pragma unroll
    for (int e = 0; e < 8; ++e) {
      x1[e] = b2f((u16)v1[e]);
      x2[e] = b2f((u16)v2[e]);
      ss += x1[e] * x1[e] + x2[e] * x2[e];
    }
    ss += __shfl_xor(ss, 1, 64);
    ss += __shfl_xor(ss, 2, 64);
    ss += __shfl_xor(ss, 4, 64);
    float r = rsqrtf(ss * (1.0f / 128.0f) + 1e-6f);
    const float* w = isq ? qw : kw;
    float sc = isq ? ATT_SCALE : 1.0f;
    short8 o1, o2;
#pragma unroll
    for (int e = 0; e < 8; ++e) {
      float y1 = x1[e] * r * w[d0 + e];
      float y2 = x2[e] * r * w[d0 + e + 64];
      float2 cs = tab[t * 64 + d0 + e];
      o1[e] = (short)f2b((y1 * cs.x - y2 * cs.y) * sc);
      o2[e] = (short)f2b((y2 * cs.x + y1 * cs.y) * sc);
    }
    *reinterpret_cast<short8*>(base + d0)      = o1;
    *reinterpret_cast<short8*>(base + d0 + 64) = o2;
    return;
  }
  blk -= 10240;
  if (blk < 8192) {                        // ---- tr_v: [b][s][kvh][d] -> [b][kvh][d][s]
    int xx = blk & 3, rest = blk >> 2;
    int yy = rest & 15, bh = rest >> 4;
    int b = bh >> 3, kvh = bh & 7;
    int d0 = xx * 32, s0 = yy * 32;
    int tx = tid & 31, ty = tid >> 5;
#pragma unroll
    for (int i = 0; i < 32; i += 8)
      utile[ty + i][tx] = qkv[(size_t)(b * S + s0 + ty + i) * NQKV + 5120 + kvh * 128 + d0 + tx];
    __syncthreads();
#pragma unroll
    for (int i = 0; i < 32; i += 8)
      vt[((size_t)(bh * 128 + d0 + ty + i)) * S + s0 + tx] = utile[tx][ty + i];
    return;
  }
  blk -= 8192;                             // ---- tr Wo -> wot (WT region, post-GEMM1)
  int bx = blk & 127, by = blk >> 7;
  int tx = tid & 31, ty = tid >> 5;
  int n0 = bx * 32, k0 = by * 32;
#pragma unroll
  for (int i = 0; i < 32; i += 8)
    ftile[ty + i][tx] = Wo[(size_t)(k0 + ty + i) * 4096 + n0 + tx];
  __syncthreads();
#pragma unroll
  for (int i = 0; i < 32; i += 8)
    wot[(size_t)(n0 + ty + i) * 4096 + k0 + tx] = f2b(ftile[tx][ty + i]);
}

// =======================================================================================
// 256x256 GEMM, TWO-phase per K-tile (round-13). Barrier-reduction axis (confirmed r12).
// Rotation: tile t, phase A stages {B-h0(t+1), A-h1(t+1)} (other buf; protected by tile
// t-1 end barrier); phase B stages {A-h0(t+2), B-h1(t+2)} (same buf; regions read only
// in phase A -> protected by the mid barrier). Phase B reads A-h1 (staged at (t-1).A,
// landed via tile t-1's vmcnt(4)). vmcnt(4): tile t+1 complete when all but phase-B's
// own 4 loads landed (2 loads/stage). Tail clamp re-writes identical bytes (benign).
// =======================================================================================
template <int OUT_BF16>
__global__ __launch_bounds__(512, 2) void k_gemm8(const u16* __restrict__ A,
                                                  const u16* __restrict__ Bm,
                                                  void* __restrict__ Cv,
                                                  int M, int N, int K) {
  __shared__ alignas(16) u16 lds[2][2][256 * 64];   // [buf][A/B][row*64+col]
  const int tid  = threadIdx.x;
  const int lane = tid & 63;
  const int wave = tid >> 6;
  const int r16 = lane & 15, h4 = lane >> 4;
  const int wm = (wave >> 2) * 128, wn = (wave & 3) * 64;

  const int nbx = N >> 8;
  const int nby = M >> 8;
  const int nwg = nby * nbx;
  const int cpx = nwg >> 3;
  const int wg  = blockIdx.x;
  const int gidx = (wg & 7) * cpx + (wg >> 3);
  const int by = gidx % nby;
  const int bx = gidx / nby;
  const int m0 = by << 8, n0 = bx << 8;

  const int NKT = K >> 6;
  const int NIT = NKT >> 1;

  f32x4 acc[8][4] = {};
  short8 af[4][2];
  short8 bfr[4][2];

  // stage s: ts = s>>2 (clamped), sel = s&3: 0=A-h0 1=B-h1 2=A-h1 3=B-h0
  auto stage = [&](int s) {
    int ts = s >> 2; if (ts > NKT - 1) ts = NKT - 1;
    const int sel  = s & 3;
    const int isB  = sel & 1;
    const int half = (sel == 1 || sel == 2) ? 1 : 0;
    const u16* G = isB ? Bm : A;
    const int base0 = isB ? n0 : m0;
    u16* lb = &lds[ts & 1][isB][0];
    const int k0 = ts << 6;
#pragma unroll
    for (int j = 0; j < 2; ++j) {
      int c = (j << 9) + tid;             // 0..1023 chunks
      int rl = c >> 3, kcd = c & 7;
      int row = isB ? ((rl & 31) | (half << 5) | ((rl >> 5) << 6))
                    : ((rl & 63) | (half << 6) | ((rl >> 6) << 7));
      int kc = kcd ^ (row & 7);
      async16(G + (size_t)(base0 + row) * K + k0 + (kc << 3),
              lb + row * 64 + (kcd << 3));
    }
  };
  auto ldA = [&](int buf, int mf, int ks) {
    int row = wm + mf * 16 + r16;
    int kc = ((ks << 2) + h4) ^ (r16 & 7);
    return *reinterpret_cast<const short8*>(&lds[buf][0][row * 64 + (kc << 3)]);
  };
  auto ldB = [&](int buf, int nf, int ks) {
    int row = wn + nf * 16 + r16;
    int kc = ((ks << 2) + h4) ^ (r16 & 7);
    return *reinterpret_cast<const short8*>(&lds[buf][1][row * 64 + (kc << 3)]);
  };

  // prologue: tile0 all 4 halves (s=0..3) + tile1 {A-h0, B-h1} (s=4,5)
#pragma unroll
  for (int s = 0; s < 6; ++s) stage(s);
  asm volatile("s_waitcnt vmcnt(4)" ::: "memory");
  __builtin_amdgcn_s_barrier();

  for (int i = 0; i < NIT; ++i) {
#pragma unroll
    for (int ph = 0; ph < 2; ++ph) {
      const int t = i * 2 + ph;
      const int buf = ph;
      // ---- Phase A: read A0-3 + B0-3, stage A-h1(t+1), B-h0(t+1), MFMA mf0-3 ----
#pragma unroll
      for (int mf = 0; mf < 4; ++mf)
#pragma unroll
        for (int ks = 0; ks < 2; ++ks) af[mf][ks] = ldA(buf, mf, ks);
#pragma unroll
      for (int nf = 0; nf < 4; ++nf)
#pragma unroll
        for (int ks = 0; ks < 2; ++ks) bfr[nf][ks] = ldB(buf, nf, ks);
      stage(4 * t + 6);                   // A-h1(t+1)  (sel 2)
      stage(4 * t + 7);                   // B-h0(t+1)  (sel 3)
      __builtin_amdgcn_s_setprio(1);
#pragma unroll
      for (int mf = 0; mf < 4; ++mf)
#pragma unroll
        for (int nf = 0; nf < 4; ++nf)
#pragma unroll
          for (int ks = 0; ks < 2; ++ks)
            acc[mf][nf] = __builtin_amdgcn_mfma_f32_16x16x32_bf16(
                af[mf][ks], bfr[nf][ks], acc[mf][nf], 0, 0, 0);
      __builtin_amdgcn_s_setprio(0);
      __builtin_amdgcn_s_barrier();
      // ---- Phase B: read A4-7, stage A-h0(t+2), B-h1(t+2), MFMA mf4-7 ----
#pragma unroll
      for (int mf = 0; mf < 4; ++mf)
#pragma unroll
        for (int ks = 0; ks < 2; ++ks) af[mf][ks] = ldA(buf, 4 + mf, ks);
      stage(4 * t + 8);                   // A-h0(t+2)  (sel 0)
      stage(4 * t + 9);                   // B-h1(t+2)  (sel 1)
      __builtin_amdgcn_s_setprio(1);
#pragma unroll
      for (int mf = 0; mf < 4; ++mf)
#pragma unroll
        for (int nf = 0; nf < 4; ++nf)
#pragma unroll
          for (int ks = 0; ks < 2; ++ks)
            acc[4 + mf][nf] = __builtin_amdgcn_mfma_f32_16x16x32_bf16(
                af[mf][ks], bfr[nf][ks], acc[4 + mf][nf], 0, 0, 0);
      __builtin_amdgcn_s_setprio(0);
      asm volatile("s_waitcnt vmcnt(4)" ::: "memory");
      __builtin_amdgcn_s_barrier();
    }
  }

  if (OUT_BF16) {
    u16* C = (u16*)Cv;
#pragma unroll
    for (int mf = 0; mf < 8; ++mf)
#pragma unroll
      for (int nf = 0; nf < 4; ++nf)
#pragma unroll
        for (int r = 0; r < 4; ++r) {
          size_t row = m0 + wm + mf * 16 + h4 * 4 + r;
          size_t col = n0 + wn + nf * 16 + r16;
          C[row * N + col] = f2b(acc[mf][nf][r]);
        }
  } else {
    float* C = (float*)Cv;
#pragma unroll
    for (int mf = 0; mf < 8; ++mf)
#pragma unroll
      for (int nf = 0; nf < 4; ++nf)
#pragma unroll
        for (int r = 0; r < 4; ++r) {
          size_t row = m0 + wm + mf * 16 + h4 * 4 + r;
          size_t col = n0 + wn + nf * 16 + r16;
          C[row * N + col] = acc[mf][nf][r];
        }
  }
}

// =======================================================================================
// Flash attention v5 + LPT (round-12, frozen).
// =======================================================================================
__global__ __launch_bounds__(256) void k_attn(const u16* __restrict__ qkv,
                                              const u16* __restrict__ vt,
                                              u16* __restrict__ out) {
  __shared__ alignas(16) u16 Klds[2][64 * 128];   // [buf][key][d] swizzled
  __shared__ alignas(16) u16 Vlds[2][128 * 64];   // [buf][d][key] swizzled
  __shared__ alignas(16) u16 Plds[4][2][16 * 64]; // [wave][rf][q(16)][key(64)] swizzled
  const int qt = 15 - blockIdx.x;                 // LPT: longest first
  const int kvh = blockIdx.y, b = blockIdx.z;
  const int tid = threadIdx.x, lane = tid & 63, wave = tid >> 6;
  const int r16 = lane & 15, h4 = lane >> 4;
  const int h = kvh * 4 + wave;
  const int qr0 = qt * 32;

  auto stageKV = [&](int t, int buf) {
    const int k0 = t << 6;
    const u16* kg = qkv + (size_t)(b * S + k0) * NQKV + 4096 + kvh * 128;
#pragma unroll
    for (int it = 0; it < 4; ++it) {
      int c = tid + (it << 8);            // 0..1023 chunks of 16B
      int key = c >> 4, c8 = c & 15;
      int jc = c8 ^ (key & 7);
      async16(kg + (size_t)key * NQKV + jc * 8, &Klds[buf][c * 8]);
    }
    const u16* vg = vt + (size_t)(b * 8 + kvh) * 128 * S + k0;
#pragma unroll
    for (int it = 0; it < 4; ++it) {
      int c = tid + (it << 8);
      int d = c >> 3, c8 = c & 7;
      int jc = c8 ^ (d & 7);
      async16(vg + (size_t)d * S + jc * 8, &Vlds[buf][c * 8]);
    }
  };
  auto ldK = [&](int buf, int f, int s4) {   // A-frag: row = key, kchunk = h4
    int key = f * 16 + r16;
    int idx = (key * 128 + s4 * 32 + h4 * 8) ^ ((key & 7) << 3);
    return *reinterpret_cast<const short8*>(&Klds[buf][idx]);
  };
  auto ldV = [&](int buf, int df, int ks) {  // A-frag: row = d, kchunk(keys) = h4
    int d = df * 16 + r16;
    int idx = (d * 64 + ks * 32 + h4 * 8) ^ ((d & 7) << 3);
    return *reinterpret_cast<const short8*>(&Vlds[buf][idx]);
  };

  // Q fragments as B-operand: col = q-row (r16), kchunk = h4.
  short8 qf[2][4];
#pragma unroll
  for (int rf = 0; rf < 2; ++rf) {
    const u16* qrow = qkv + (size_t)(b * S + qr0 + rf * 16 + r16) * NQKV + h * 128 + h4 * 8;
#pragma unroll
    for (int s4 = 0; s4 < 4; ++s4)
      qf[rf][s4] = *reinterpret_cast<const short8*>(qrow + s4 * 32);
  }

  float mrow[2] = {-INFINITY, -INFINITY};
  float lrow[2] = {0.f, 0.f};
  f32x4 o[2][8] = {};    // O^T frags: o[rf][df], col = q-row, regs = d-sub

  const int ntiles = (qt >> 1) + 1;
  stageKV(0, 0);
  __syncthreads();

  for (int t = 0; t < ntiles; ++t) {
    const int buf = t & 1;
    if (t + 1 < ntiles) stageKV(t + 1, buf ^ 1);
    const int k0 = t << 6;
    const bool diag = (t == ntiles - 1);
    int fa0 = 4, fa1 = 4;
    if (diag) {
      fa0 = ((qr0 - k0 + 15) >> 4) + 1; if (fa0 > 4) fa0 = 4;
      fa1 = ((qr0 - k0 + 31) >> 4) + 1; if (fa1 > 4) fa1 = 4;
    }
    const int ks_act = (fa1 + 1) >> 1;

    // S^T = K Q^T : sacc[rf][f] cols = q-rows, regs = keys (f*16 + h4*4 + r)
    f32x4 sacc[2][4] = {};
    __builtin_amdgcn_s_setprio(1);
#pragma unroll
    for (int f = 0; f < 4; ++f) {
      if (f < fa1) {
        short8 kf[4];
#pragma unroll
        for (int s4 = 0; s4 < 4; ++s4) kf[s4] = ldK(buf, f, s4);
#pragma unroll
        for (int s4 = 0; s4 < 4; ++s4) {
          if (f < fa0)
            sacc[0][f] = __builtin_amdgcn_mfma_f32_16x16x32_bf16(kf[s4], qf[0][s4], sacc[0][f], 0, 0, 0);
          sacc[1][f] = __builtin_amdgcn_mfma_f32_16x16x32_bf16(kf[s4], qf[1][s4], sacc[1][f], 0, 0, 0);
        }
      }
    }
    __builtin_amdgcn_s_setprio(0);
    // causal mask (all frags incl. skipped ones: they become exp()=0)
    if (diag) {
#pragma unroll
      for (int rf = 0; rf < 2; ++rf)
#pragma unroll
        for (int f = 0; f < 4; ++f)
#pragma unroll
          for (int r = 0; r < 4; ++r) {
            int key = k0 + f * 16 + h4 * 4 + r;
            int row = qr0 + rf * 16 + r16;
            if (key > row) sacc[rf][f][r] = -1e30f;
          }
    }
    // online softmax with defer-max (T13)
#pragma unroll
    for (int rf = 0; rf < 2; ++rf) {
      float mx = sacc[rf][0][0];
#pragma unroll
      for (int f = 0; f < 4; ++f)
#pragma unroll
        for (int r = 0; r < 4; ++r) mx = fmaxf(mx, sacc[rf][f][r]);
      mx = fmaxf(mx, __shfl_xor(mx, 16, 64));
      mx = fmaxf(mx, __shfl_xor(mx, 32, 64));
      if (!__all(mx - mrow[rf] <= 8.0f)) {
        float mn = fmaxf(mrow[rf], mx);
        float fac = __expf(mrow[rf] - mn);
        mrow[rf] = mn;
        lrow[rf] *= fac;
#pragma unroll
        for (int df = 0; df < 8; ++df)
#pragma unroll
          for (int r = 0; r < 4; ++r) o[rf][df][r] *= fac;
      }
      float psum = 0.f;
#pragma unroll
      for (int f = 0; f < 4; ++f)
#pragma unroll
        for (int r = 0; r < 4; ++r) {
          float p = __expf(sacc[rf][f][r] - mrow[rf]);
          sacc[rf][f][r] = p;
          psum += p;
        }
      psum += __shfl_xor(psum, 16, 64);
      psum += __shfl_xor(psum, 32, 64);
      lrow[rf] += psum;
    }

    // P^T -> per-wave LDS: cvt_pk pairs + b64 writes
#pragma unroll
    for (int rf = 0; rf < 2; ++rf)
#pragma unroll
      for (int f = 0; f < 4; ++f) {
        uint2 w;
        w.x = cvt_pk_bf16(sacc[rf][f][0], sacc[rf][f][1]);
        w.y = cvt_pk_bf16(sacc[rf][f][2], sacc[rf][f][3]);
        int idx = r16 * 64 + ((f * 16 + h4 * 4) ^ ((r16 & 7) << 3));
        *reinterpret_cast<uint2*>(&Plds[wave][rf][idx]) = w;
      }
    // P^T B-frags
    short8 pf[2][2];
#pragma unroll
    for (int rf = 0; rf < 2; ++rf)
#pragma unroll
      for (int ks = 0; ks < 2; ++ks)
        if (ks < ks_act) {
          int idx = r16 * 64 + ((ks * 32 + h4 * 8) ^ ((r16 & 7) << 3));
          pf[rf][ks] = *reinterpret_cast<const short8*>(&Plds[wave][rf][idx]);
        }
    // O^T += V^T P^T
    __builtin_amdgcn_s_setprio(1);
#pragma unroll
    for (int df = 0; df < 8; ++df)
#pragma unroll
      for (int ks = 0; ks < 2; ++ks)
        if (ks < ks_act) {
          short8 vf = ldV(buf, df, ks);
#pragma unroll
          for (int rf = 0; rf < 2; ++rf)
            o[rf][df] = __builtin_amdgcn_mfma_f32_16x16x32_bf16(vf, pf[rf][ks], o[rf][df], 0, 0, 0);
        }
    __builtin_amdgcn_s_setprio(0);
    __syncthreads();
  }

  // epilogue: lane owns q-row r16 (per rf); packed stores
#pragma unroll
  for (int rf = 0; rf < 2; ++rf) {
    float rinv = 1.0f / lrow[rf];
    int row = qr0 + rf * 16 + r16;
    u16* orow = out + (size_t)(b * S + row) * 4096 + h * 128;
#pragma unroll
    for (int df = 0; df < 8; ++df) {
      unsigned p0 = cvt_pk_bf16(o[rf][df][0] * rinv, o[rf][df][1] * rinv);
      unsigned p1 = cvt_pk_bf16(o[rf][df][2] * rinv, o[rf][df][3] * rinv);
      uint2 pk; pk.x = p0; pk.y = p1;
      *reinterpret_cast<uint2*>(orow + df * 16 + h4 * 4) = pk;
    }
  }
}

// ---------------------------------------------------------------------------------------
extern "C" void kernel_launch(void* const* d_in, const int* in_sizes, int n_in,
                              void* d_out, int out_size, void* d_ws, size_t ws_size,
                              hipStream_t stream) {
  const float* hs  = (const float*)d_in[0];
  const int*   pos = (const int*)d_in[1];
  const float* Wq  = (const float*)d_in[2];
  const float* Wk  = (const float*)d_in[3];
  const float* Wv  = (const float*)d_in[4];
  const float* Wo  = (const float*)d_in[5];
  const float* qnw = (const float*)d_in[6];
  const float* knw = (const float*)d_in[7];

  char* ws = (char*)d_ws;
  u16*   X    = (u16*)(ws);
  u16*   WT   = (u16*)(ws + 67108864);
  u16*   QKV  = (u16*)(ws + 117440512);
  u16*   VT   = (u16*)(ws + 218103808);
  float2* TAB = (float2*)(ws + 234881024);
  u16*   ATTN = X;
  u16*   WOT  = WT;

  // 1. fused prep: cvt X | rope_tab | tr Wq | tr Wk | tr Wv  (59392 blocks)
  k_prep<<<59392, 256, 0, stream>>>(hs, Wq, Wk, Wv, pos, X, WT, TAB);
  // 2. QKV GEMM (2-phase 256^2): [8192,4096] x [6144,4096]^T -> bf16 qkv
  k_gemm8<1><<<(8192 / 256) * (6144 / 256), 512, 0, stream>>>(X, WT, QKV, 8192, 6144, 4096);
  // 3. fused post: norm_rope | tr_v | tr Wo  (34816 blocks)
  k_post<<<34816, 256, 0, stream>>>(QKV, TAB, qnw, knw, VT, Wo, WOT);
  // 4. attention -> ATTN (LPT order)
  k_attn<<<dim3(16, 8, 16), 256, 0, stream>>>(QKV, VT, ATTN);
  // 5. output projection (2-phase 256^2) -> d_out (f32)
  k_gemm8<0><<<(8192 / 256) * (4096 / 256), 512, 0, stream>>>(ATTN, WOT, d_out, 8192, 4096, 4096);
}

// Round 14
// 799.855 us; speedup vs baseline: 1.0675x; 1.0675x over previous
//
#include <hip/hip_runtime.h>

typedef unsigned short u16;
typedef __attribute__((ext_vector_type(4))) unsigned short u16x4;
typedef __attribute__((ext_vector_type(8))) short short8;
typedef __attribute__((ext_vector_type(4))) float f32x4;

#define DEV static __device__ __forceinline__

constexpr int NB   = 16;
constexpr int S    = 512;
constexpr int DM   = 4096;
constexpr int NH   = 32;
constexpr int NKV  = 8;
constexpr int HD   = 128;
constexpr int TOK  = NB * S;          // 8192
constexpr int NQKV = 6144;            // 4096 q + 1024 k + 1024 v
constexpr float ATT_SCALE = 0.08838834764831845f;  // 1/sqrt(128)

DEV u16 f2b(float f) {
  union { float f; unsigned u; } v; v.f = f;
  unsigned r = v.u + 0x7fffu + ((v.u >> 16) & 1u);
  return (u16)(r >> 16);
}
DEV float b2f(u16 u) {
  union { unsigned u; float f; } v; v.u = ((unsigned)u) << 16;
  return v.f;
}
DEV unsigned cvt_pk_bf16(float lo, float hi) {
  unsigned r;
  asm("v_cvt_pk_bf16_f32 %0, %1, %2" : "=v"(r) : "v"(lo), "v"(hi));
  return r;
}
DEV void async16(const void* g, void* l) {
  __builtin_amdgcn_global_load_lds(
      (const __attribute__((address_space(1))) unsigned int*)g,
      (__attribute__((address_space(3))) unsigned int*)l, 16, 0, 0);
}

// =======================================================================================
// Fused pre-GEMM prep (1 launch): cvt X | rope_tab | tr_w Wq | tr_w Wk | tr_w Wv.
// =======================================================================================
__global__ __launch_bounds__(256) void k_prep(const float* __restrict__ hs,
                                              const float* __restrict__ Wq,
                                              const float* __restrict__ Wk,
                                              const float* __restrict__ Wv,
                                              const int* __restrict__ pos,
                                              u16* __restrict__ X,
                                              u16* __restrict__ WT,
                                              float2* __restrict__ tab) {
  __shared__ float tile[32][33];
  int blk = blockIdx.x;
  const int tid = threadIdx.x;
  if (blk < 32768) {                       // ---- cvt X: f32 -> bf16, float4/lane
    int i = (blk * 256 + tid) * 4;
    const float4 v = *reinterpret_cast<const float4*>(hs + i);
    u16x4 o;
    o[0] = f2b(v.x); o[1] = f2b(v.y); o[2] = f2b(v.z); o[3] = f2b(v.w);
    *reinterpret_cast<u16x4*>(X + i) = o;
    return;
  }
  blk -= 32768;
  if (blk < 2048) {                        // ---- RoPE cos/sin table (4 tokens/block)
    int t = blk * 4 + (tid >> 6);
    int j = tid & 63;
    float p = (float)pos[t];
    float inv = expf(-(float)j * 0.21586735246819178f);
    float sv, cv;
    sincosf(p * inv, &sv, &cv);
    tab[t * 64 + j] = make_float2(cv, sv);
    return;
  }
  blk -= 2048;
  const float* src; u16* dst; int ncols, bx, by;
  if (blk < 16384) {                       // ---- tr Wq
    src = Wq; dst = WT; ncols = 4096; bx = blk & 127; by = blk >> 7;
  } else if (blk < 20480) {                // ---- tr Wk
    blk -= 16384;
    src = Wk; dst = WT + (size_t)4096 * 4096; ncols = 1024; bx = blk & 31; by = blk >> 5;
  } else {                                 // ---- tr Wv
    blk -= 20480;
    src = Wv; dst = WT + (size_t)5120 * 4096; ncols = 1024; bx = blk & 31; by = blk >> 5;
  }
  const int tx = tid & 31, ty = tid >> 5;
  const int n0 = bx * 32, k0 = by * 32;
#pragma unroll
  for (int i = 0; i < 32; i += 8)
    tile[ty + i][tx] = src[(size_t)(k0 + ty + i) * ncols + n0 + tx];
  __syncthreads();
#pragma unroll
  for (int i = 0; i < 32; i += 8)
    dst[(size_t)(n0 + ty + i) * 4096 + k0 + tx] = f2b(tile[tx][ty + i]);
}

// =======================================================================================
// Fused post-GEMM1 prep (1 launch): norm_rope | tr_v | tr_w Wo.
// =======================================================================================
__global__ __launch_bounds__(256) void k_post(u16* __restrict__ qkv,
                                              const float2* __restrict__ tab,
                                              const float* __restrict__ qw,
                                              const float* __restrict__ kw,
                                              u16* __restrict__ vt,
                                              const float* __restrict__ Wo,
                                              u16* __restrict__ wot) {
  __shared__ float ftile[32][33];
  __shared__ u16 utile[32][33];
  int blk = blockIdx.x;
  const int tid = threadIdx.x;
  if (blk < 10240) {                       // ---- fused RMSNorm + RoPE (vectorized)
    int wid  = blk * 4 + (tid >> 6);
    int lane = tid & 63;
    int gr = wid * 8 + (lane >> 3);
    int t  = gr / 40;
    int hh = gr - t * 40;
    bool isq = hh < 32;
    u16* base = qkv + (size_t)t * NQKV + (isq ? hh * 128 : 4096 + (hh - 32) * 128);
    int d0 = (lane & 7) * 8;
    short8 v1 = *reinterpret_cast<const short8*>(base + d0);
    short8 v2 = *reinterpret_cast<const short8*>(base + d0 + 64);
    float x1[8], x2[8];
    float ss = 0.f;
#pragma unroll
    for (int e = 0; e < 8; ++e) {
      x1[e] = b2f((u16)v1[e]);
      x2[e] = b2f((u16)v2[e]);
      ss += x1[e] * x1[e] + x2[e] * x2[e];
    }
    ss += __shfl_xor(ss, 1, 64);
    ss += __shfl_xor(ss, 2, 64);
    ss += __shfl_xor(ss, 4, 64);
    float r = rsqrtf(ss * (1.0f / 128.0f) + 1e-6f);
    const float* w = isq ? qw : kw;
    float sc = isq ? ATT_SCALE : 1.0f;
    short8 o1, o2;
#pragma unroll
    for (int e = 0; e < 8; ++e) {
      float y1 = x1[e] * r * w[d0 + e];
      float y2 = x2[e] * r * w[d0 + e + 64];
      float2 cs = tab[t * 64 + d0 + e];
      o1[e] = (short)f2b((y1 * cs.x - y2 * cs.y) * sc);
      o2[e] = (short)f2b((y2 * cs.x + y1 * cs.y) * sc);
    }
    *reinterpret_cast<short8*>(base + d0)      = o1;
    *reinterpret_cast<short8*>(base + d0 + 64) = o2;
    return;
  }
  blk -= 10240;
  if (blk < 8192) {                        // ---- tr_v: [b][s][kvh][d] -> [b][kvh][d][s]
    int xx = blk & 3, rest = blk >> 2;
    int yy = rest & 15, bh = rest >> 4;
    int b = bh >> 3, kvh = bh & 7;
    int d0 = xx * 32, s0 = yy * 32;
    int tx = tid & 31, ty = tid >> 5;
#pragma unroll
    for (int i = 0; i < 32; i += 8)
      utile[ty + i][tx] = qkv[(size_t)(b * S + s0 + ty + i) * NQKV + 5120 + kvh * 128 + d0 + tx];
    __syncthreads();
#pragma unroll
    for (int i = 0; i < 32; i += 8)
      vt[((size_t)(bh * 128 + d0 + ty + i)) * S + s0 + tx] = utile[tx][ty + i];
    return;
  }
  blk -= 8192;                             // ---- tr Wo -> wot (WT region, post-GEMM1)
  int bx = blk & 127, by = blk >> 7;
  int tx = tid & 31, ty = tid >> 5;
  int n0 = bx * 32, k0 = by * 32;
#pragma unroll
  for (int i = 0; i < 32; i += 8)
    ftile[ty + i][tx] = Wo[(size_t)(k0 + ty + i) * 4096 + n0 + tx];
  __syncthreads();
#pragma unroll
  for (int i = 0; i < 32; i += 8)
    wot[(size_t)(n0 + ty + i) * 4096 + k0 + tx] = f2b(ftile[tx][ty + i]);
}

// =======================================================================================
// 256x256 GEMM, TWO-phase per K-tile (round-13, FROZEN -- best verified: 338us, 56%).
// =======================================================================================
template <int OUT_BF16>
__global__ __launch_bounds__(512, 2) void k_gemm8(const u16* __restrict__ A,
                                                  const u16* __restrict__ Bm,
                                                  void* __restrict__ Cv,
                                                  int M, int N, int K) {
  __shared__ alignas(16) u16 lds[2][2][256 * 64];   // [buf][A/B][row*64+col]
  const int tid  = threadIdx.x;
  const int lane = tid & 63;
  const int wave = tid >> 6;
  const int r16 = lane & 15, h4 = lane >> 4;
  const int wm = (wave >> 2) * 128, wn = (wave & 3) * 64;

  const int nbx = N >> 8;
  const int nby = M >> 8;
  const int nwg = nby * nbx;
  const int cpx = nwg >> 3;
  const int wg  = blockIdx.x;
  const int gidx = (wg & 7) * cpx + (wg >> 3);
  const int by = gidx % nby;
  const int bx = gidx / nby;
  const int m0 = by << 8, n0 = bx << 8;

  const int NKT = K >> 6;
  const int NIT = NKT >> 1;

  f32x4 acc[8][4] = {};
  short8 af[4][2];
  short8 bfr[4][2];

  // stage s: ts = s>>2 (clamped), sel = s&3: 0=A-h0 1=B-h1 2=A-h1 3=B-h0
  auto stage = [&](int s) {
    int ts = s >> 2; if (ts > NKT - 1) ts = NKT - 1;
    const int sel  = s & 3;
    const int isB  = sel & 1;
    const int half = (sel == 1 || sel == 2) ? 1 : 0;
    const u16* G = isB ? Bm : A;
    const int base0 = isB ? n0 : m0;
    u16* lb = &lds[ts & 1][isB][0];
    const int k0 = ts << 6;
#pragma unroll
    for (int j = 0; j < 2; ++j) {
      int c = (j << 9) + tid;             // 0..1023 chunks
      int rl = c >> 3, kcd = c & 7;
      int row = isB ? ((rl & 31) | (half << 5) | ((rl >> 5) << 6))
                    : ((rl & 63) | (half << 6) | ((rl >> 6) << 7));
      int kc = kcd ^ (row & 7);
      async16(G + (size_t)(base0 + row) * K + k0 + (kc << 3),
              lb + row * 64 + (kcd << 3));
    }
  };
  auto ldA = [&](int buf, int mf, int ks) {
    int row = wm + mf * 16 + r16;
    int kc = ((ks << 2) + h4) ^ (r16 & 7);
    return *reinterpret_cast<const short8*>(&lds[buf][0][row * 64 + (kc << 3)]);
  };
  auto ldB = [&](int buf, int nf, int ks) {
    int row = wn + nf * 16 + r16;
    int kc = ((ks << 2) + h4) ^ (r16 & 7);
    return *reinterpret_cast<const short8*>(&lds[buf][1][row * 64 + (kc << 3)]);
  };

  // prologue: tile0 all 4 halves (s=0..3) + tile1 {A-h0, B-h1} (s=4,5)
#pragma unroll
  for (int s = 0; s < 6; ++s) stage(s);
  asm volatile("s_waitcnt vmcnt(4)" ::: "memory");
  __builtin_amdgcn_s_barrier();

  for (int i = 0; i < NIT; ++i) {
#pragma unroll
    for (int ph = 0; ph < 2; ++ph) {
      const int t = i * 2 + ph;
      const int buf = ph;
      // ---- Phase A: read A0-3 + B0-3, stage A-h1(t+1), B-h0(t+1), MFMA mf0-3 ----
#pragma unroll
      for (int mf = 0; mf < 4; ++mf)
#pragma unroll
        for (int ks = 0; ks < 2; ++ks) af[mf][ks] = ldA(buf, mf, ks);
#pragma unroll
      for (int nf = 0; nf < 4; ++nf)
#pragma unroll
        for (int ks = 0; ks < 2; ++ks) bfr[nf][ks] = ldB(buf, nf, ks);
      stage(4 * t + 6);                   // A-h1(t+1)  (sel 2)
      stage(4 * t + 7);                   // B-h0(t+1)  (sel 3)
      __builtin_amdgcn_s_setprio(1);
#pragma unroll
      for (int mf = 0; mf < 4; ++mf)
#pragma unroll
        for (int nf = 0; nf < 4; ++nf)
#pragma unroll
          for (int ks = 0; ks < 2; ++ks)
            acc[mf][nf] = __builtin_amdgcn_mfma_f32_16x16x32_bf16(
                af[mf][ks], bfr[nf][ks], acc[mf][nf], 0, 0, 0);
      __builtin_amdgcn_s_setprio(0);
      __builtin_amdgcn_s_barrier();
      // ---- Phase B: read A4-7, stage A-h0(t+2), B-h1(t+2), MFMA mf4-7 ----
#pragma unroll
      for (int mf = 0; mf < 4; ++mf)
#pragma unroll
        for (int ks = 0; ks < 2; ++ks) af[mf][ks] = ldA(buf, 4 + mf, ks);
      stage(4 * t + 8);                   // A-h0(t+2)  (sel 0)
      stage(4 * t + 9);                   // B-h1(t+2)  (sel 1)
      __builtin_amdgcn_s_setprio(1);
#pragma unroll
      for (int mf = 0; mf < 4; ++mf)
#pragma unroll
        for (int nf = 0; nf < 4; ++nf)
#pragma unroll
          for (int ks = 0; ks < 2; ++ks)
            acc[4 + mf][nf] = __builtin_amdgcn_mfma_f32_16x16x32_bf16(
                af[mf][ks], bfr[nf][ks], acc[4 + mf][nf], 0, 0, 0);
      __builtin_amdgcn_s_setprio(0);
      asm volatile("s_waitcnt vmcnt(4)" ::: "memory");
      __builtin_amdgcn_s_barrier();
    }
  }

  if (OUT_BF16) {
    u16* C = (u16*)Cv;
#pragma unroll
    for (int mf = 0; mf < 8; ++mf)
#pragma unroll
      for (int nf = 0; nf < 4; ++nf)
#pragma unroll
        for (int r = 0; r < 4; ++r) {
          size_t row = m0 + wm + mf * 16 + h4 * 4 + r;
          size_t col = n0 + wn + nf * 16 + r16;
          C[row * N + col] = f2b(acc[mf][nf][r]);
        }
  } else {
    float* C = (float*)Cv;
#pragma unroll
    for (int mf = 0; mf < 8; ++mf)
#pragma unroll
      for (int nf = 0; nf < 4; ++nf)
#pragma unroll
        for (int r = 0; r < 4; ++r) {
          size_t row = m0 + wm + mf * 16 + h4 * 4 + r;
          size_t col = n0 + wn + nf * 16 + r16;
          C[row * N + col] = acc[mf][nf][r];
        }
  }
}

// =======================================================================================
// Flash attention v5. Round-14 fix: LPT was ineffective in r12 -- qt was mapped to
// blockIdx.x, the FASTEST grid dim, so dispatch order still interleaved long/short
// blocks. Grid is now (kvh, b, qt) with qt = 15 - blockIdx.z (slowest dim): all 9-tile
// blocks genuinely launch first, short blocks back-fill the tail. Body frozen (r8).
// =======================================================================================
__global__ __launch_bounds__(256) void k_attn(const u16* __restrict__ qkv,
                                              const u16* __restrict__ vt,
                                              u16* __restrict__ out) {
  __shared__ alignas(16) u16 Klds[2][64 * 128];   // [buf][key][d] swizzled
  __shared__ alignas(16) u16 Vlds[2][128 * 64];   // [buf][d][key] swizzled
  __shared__ alignas(16) u16 Plds[4][2][16 * 64]; // [wave][rf][q(16)][key(64)] swizzled
  const int kvh = blockIdx.x, b = blockIdx.y;
  const int qt = 15 - blockIdx.z;                 // LPT: longest first (slowest dim)
  const int tid = threadIdx.x, lane = tid & 63, wave = tid >> 6;
  const int r16 = lane & 15, h4 = lane >> 4;
  const int h = kvh * 4 + wave;
  const int qr0 = qt * 32;

  auto stageKV = [&](int t, int buf) {
    const int k0 = t << 6;
    const u16* kg = qkv + (size_t)(b * S + k0) * NQKV + 4096 + kvh * 128;
#pragma unroll
    for (int it = 0; it < 4; ++it) {
      int c = tid + (it << 8);            // 0..1023 chunks of 16B
      int key = c >> 4, c8 = c & 15;
      int jc = c8 ^ (key & 7);
      async16(kg + (size_t)key * NQKV + jc * 8, &Klds[buf][c * 8]);
    }
    const u16* vg = vt + (size_t)(b * 8 + kvh) * 128 * S + k0;
#pragma unroll
    for (int it = 0; it < 4; ++it) {
      int c = tid + (it << 8);
      int d = c >> 3, c8 = c & 7;
      int jc = c8 ^ (d & 7);
      async16(vg + (size_t)d * S + jc * 8, &Vlds[buf][c * 8]);
    }
  };
  auto ldK = [&](int buf, int f, int s4) {   // A-frag: row = key, kchunk = h4
    int key = f * 16 + r16;
    int idx = (key * 128 + s4 * 32 + h4 * 8) ^ ((key & 7) << 3);
    return *reinterpret_cast<const short8*>(&Klds[buf][idx]);
  };
  auto ldV = [&](int buf, int df, int ks) {  // A-frag: row = d, kchunk(keys) = h4
    int d = df * 16 + r16;
    int idx = (d * 64 + ks * 32 + h4 * 8) ^ ((d & 7) << 3);
    return *reinterpret_cast<const short8*>(&Vlds[buf][idx]);
  };

  // Q fragments as B-operand: col = q-row (r16), kchunk = h4.
  short8 qf[2][4];
#pragma unroll
  for (int rf = 0; rf < 2; ++rf) {
    const u16* qrow = qkv + (size_t)(b * S + qr0 + rf * 16 + r16) * NQKV + h * 128 + h4 * 8;
#pragma unroll
    for (int s4 = 0; s4 < 4; ++s4)
      qf[rf][s4] = *reinterpret_cast<const short8*>(qrow + s4 * 32);
  }

  float mrow[2] = {-INFINITY, -INFINITY};
  float lrow[2] = {0.f, 0.f};
  f32x4 o[2][8] = {};    // O^T frags: o[rf][df], col = q-row, regs = d-sub

  const int ntiles = (qt >> 1) + 1;
  stageKV(0, 0);
  __syncthreads();

  for (int t = 0; t < ntiles; ++t) {
    const int buf = t & 1;
    if (t + 1 < ntiles) stageKV(t + 1, buf ^ 1);
    const int k0 = t << 6;
    const bool diag = (t == ntiles - 1);
    int fa0 = 4, fa1 = 4;
    if (diag) {
      fa0 = ((qr0 - k0 + 15) >> 4) + 1; if (fa0 > 4) fa0 = 4;
      fa1 = ((qr0 - k0 + 31) >> 4) + 1; if (fa1 > 4) fa1 = 4;
    }
    const int ks_act = (fa1 + 1) >> 1;

    // S^T = K Q^T : sacc[rf][f] cols = q-rows, regs = keys (f*16 + h4*4 + r)
    f32x4 sacc[2][4] = {};
    __builtin_amdgcn_s_setprio(1);
#pragma unroll
    for (int f = 0; f < 4; ++f) {
      if (f < fa1) {
        short8 kf[4];
#pragma unroll
        for (int s4 = 0; s4 < 4; ++s4) kf[s4] = ldK(buf, f, s4);
#pragma unroll
        for (int s4 = 0; s4 < 4; ++s4) {
          if (f < fa0)
            sacc[0][f] = __builtin_amdgcn_mfma_f32_16x16x32_bf16(kf[s4], qf[0][s4], sacc[0][f], 0, 0, 0);
          sacc[1][f] = __builtin_amdgcn_mfma_f32_16x16x32_bf16(kf[s4], qf[1][s4], sacc[1][f], 0, 0, 0);
        }
      }
    }
    __builtin_amdgcn_s_setprio(0);
    // causal mask (all frags incl. skipped ones: they become exp()=0)
    if (diag) {
#pragma unroll
      for (int rf = 0; rf < 2; ++rf)
#pragma unroll
        for (int f = 0; f < 4; ++f)
#pragma unroll
          for (int r = 0; r < 4; ++r) {
            int key = k0 + f * 16 + h4 * 4 + r;
            int row = qr0 + rf * 16 + r16;
            if (key > row) sacc[rf][f][r] = -1e30f;
          }
    }
    // online softmax with defer-max (T13)
#pragma unroll
    for (int rf = 0; rf < 2; ++rf) {
      float mx = sacc[rf][0][0];
#pragma unroll
      for (int f = 0; f < 4; ++f)
#pragma unroll
        for (int r = 0; r < 4; ++r) mx = fmaxf(mx, sacc[rf][f][r]);
      mx = fmaxf(mx, __shfl_xor(mx, 16, 64));
      mx = fmaxf(mx, __shfl_xor(mx, 32, 64));
      if (!__all(mx - mrow[rf] <= 8.0f)) {
        float mn = fmaxf(mrow[rf], mx);
        float fac = __expf(mrow[rf] - mn);
        mrow[rf] = mn;
        lrow[rf] *= fac;
#pragma unroll
        for (int df = 0; df < 8; ++df)
#pragma unroll
          for (int r = 0; r < 4; ++r) o[rf][df][r] *= fac;
      }
      float psum = 0.f;
#pragma unroll
      for (int f = 0; f < 4; ++f)
#pragma unroll
        for (int r = 0; r < 4; ++r) {
          float p = __expf(sacc[rf][f][r] - mrow[rf]);
          sacc[rf][f][r] = p;
          psum += p;
        }
      psum += __shfl_xor(psum, 16, 64);
      psum += __shfl_xor(psum, 32, 64);
      lrow[rf] += psum;
    }

    // P^T -> per-wave LDS: cvt_pk pairs + b64 writes
#pragma unroll
    for (int rf = 0; rf < 2; ++rf)
#pragma unroll
      for (int f = 0; f < 4; ++f) {
        uint2 w;
        w.x = cvt_pk_bf16(sacc[rf][f][0], sacc[rf][f][1]);
        w.y = cvt_pk_bf16(sacc[rf][f][2], sacc[rf][f][3]);
        int idx = r16 * 64 + ((f * 16 + h4 * 4) ^ ((r16 & 7) << 3));
        *reinterpret_cast<uint2*>(&Plds[wave][rf][idx]) = w;
      }
    // P^T B-frags
    short8 pf[2][2];
#pragma unroll
    for (int rf = 0; rf < 2; ++rf)
#pragma unroll
      for (int ks = 0; ks < 2; ++ks)
        if (ks < ks_act) {
          int idx = r16 * 64 + ((ks * 32 + h4 * 8) ^ ((r16 & 7) << 3));
          pf[rf][ks] = *reinterpret_cast<const short8*>(&Plds[wave][rf][idx]);
        }
    // O^T += V^T P^T
    __builtin_amdgcn_s_setprio(1);
#pragma unroll
    for (int df = 0; df < 8; ++df)
#pragma unroll
      for (int ks = 0; ks < 2; ++ks)
        if (ks < ks_act) {
          short8 vf = ldV(buf, df, ks);
#pragma unroll
          for (int rf = 0; rf < 2; ++rf)
            o[rf][df] = __builtin_amdgcn_mfma_f32_16x16x32_bf16(vf, pf[rf][ks], o[rf][df], 0, 0, 0);
        }
    __builtin_amdgcn_s_setprio(0);
    __syncthreads();
  }

  // epilogue: lane owns q-row r16 (per rf); packed stores
#pragma unroll
  for (int rf = 0; rf < 2; ++rf) {
    float rinv = 1.0f / lrow[rf];
    int row = qr0 + rf * 16 + r16;
    u16* orow = out + (size_t)(b * S + row) * 4096 + h * 128;
#pragma unroll
    for (int df = 0; df < 8; ++df) {
      unsigned p0 = cvt_pk_bf16(o[rf][df][0] * rinv, o[rf][df][1] * rinv);
      unsigned p1 = cvt_pk_bf16(o[rf][df][2] * rinv, o[rf][df][3] * rinv);
      uint2 pk; pk.x = p0; pk.y = p1;
      *reinterpret_cast<uint2*>(orow + df * 16 + h4 * 4) = pk;
    }
  }
}

// ---------------------------------------------------------------------------------------
extern "C" void kernel_launch(void* const* d_in, const int* in_sizes, int n_in,
                              void* d_out, int out_size, void* d_ws, size_t ws_size,
                              hipStream_t stream) {
  const float* hs  = (const float*)d_in[0];
  const int*   pos = (const int*)d_in[1];
  const float* Wq  = (const float*)d_in[2];
  const float* Wk  = (const float*)d_in[3];
  const float* Wv  = (const float*)d_in[4];
  const float* Wo  = (const float*)d_in[5];
  const float* qnw = (const float*)d_in[6];
  const float* knw = (const float*)d_in[7];

  char* ws = (char*)d_ws;
  u16*   X    = (u16*)(ws);
  u16*   WT   = (u16*)(ws + 67108864);
  u16*   QKV  = (u16*)(ws + 117440512);
  u16*   VT   = (u16*)(ws + 218103808);
  float2* TAB = (float2*)(ws + 234881024);
  u16*   ATTN = X;
  u16*   WOT  = WT;

  // 1. fused prep: cvt X | rope_tab | tr Wq | tr Wk | tr Wv  (59392 blocks)
  k_prep<<<59392, 256, 0, stream>>>(hs, Wq, Wk, Wv, pos, X, WT, TAB);
  // 2. QKV GEMM (2-phase 256^2): [8192,4096] x [6144,4096]^T -> bf16 qkv
  k_gemm8<1><<<(8192 / 256) * (6144 / 256), 512, 0, stream>>>(X, WT, QKV, 8192, 6144, 4096);
  // 3. fused post: norm_rope | tr_v | tr Wo  (34816 blocks)
  k_post<<<34816, 256, 0, stream>>>(QKV, TAB, qnw, knw, VT, Wo, WOT);
  // 4. attention -> ATTN (LPT: qt in slowest grid dim)
  k_attn<<<dim3(8, 16, 16), 256, 0, stream>>>(QKV, VT, ATTN);
  // 5. output projection (2-phase 256^2) -> d_out (f32)
  k_gemm8<0><<<(8192 / 256) * (4096 / 256), 512, 0, stream>>>(ATTN, WOT, d_out, 8192, 4096, 4096);
}